// Round 17
// baseline (618.388 us; speedup 1.0000x reference)
//
#include <hip/hip_runtime.h>
#include <cstddef>

#define T_ 1024
#define B_ 128
#define F_ 243
#define H_ 20
#define G_ 60   // 3*H
#define R_ 512  // B*POOL
#define P_ 8    // xg prefetch depth / e-group size in k2
#define FP_ 256 // padded F for Wt (f-major transposed W_ih)
#define HS_ 244 // h_seq row stride: 244 floats = 976 B -> 16-B aligned rows

__device__ __forceinline__ float rdlane(float v, int l) {
  return __int_as_float(__builtin_amdgcn_readlane(__float_as_int(v), l));
}
#define RCP(x) __builtin_amdgcn_rcpf(x)
#if __has_builtin(__builtin_amdgcn_exp2f)
#define EXP2(x) __builtin_amdgcn_exp2f(x)
#else
#define EXP2(x) __expf((x) * 0.6931471805599453f)
#endif
#define NL2E_ -1.4426950408889634f   // -log2(e)
#define L2E2_ 2.8853900817779268f    // 2*log2(e)

// ---------------- K1a: streaming max-pool(4): feats -> h_seq (b-major, stride 244) -------
// Unchanged (validated r7-r16). Blocks 0..59 also build Wt[256][60].
__global__ __launch_bounds__(256) void k1a_pool(
    const float* __restrict__ feats, float* __restrict__ h_seq,
    const float* __restrict__ W_ih, float* __restrict__ Wt)
{
  const int bid = blockIdx.x;           // 16384 = 1024 t x 16 b-groups
  if (bid < 60) {                       // folded k0: 60*256 >= FP_*G_
    const int i = bid * 256 + threadIdx.x;
    if (i < FP_ * G_) {
      const int f = i / G_, g = i - f * G_;
      Wt[(size_t)f * G_ + g] = (f < F_) ? W_ih[(size_t)g * F_ + f] : 0.f;
    }
  }
  const int t = bid & (T_ - 1);
  const int b0 = (bid >> 10) << 3;      // 8 batch rows per block
  const int col = threadIdx.x;
  if (col < F_) {
    #pragma unroll
    for (int bb = 0; bb < 8; ++bb) {
      const float* p =
          feats + ((size_t)t * R_ + (size_t)(b0 + bb) * 4) * F_ + col;
      const float v =
          fmaxf(fmaxf(p[0], p[F_]), fmaxf(p[2 * F_], p[3 * F_]));
      h_seq[((size_t)(b0 + bb) * T_ + t) * HS_ + col] = v;
    }
  }
}

// ---------------- K1b: GEMM  xg = h_seq @ W_ih^T + b_ih  (unchanged, validated) ----------
__global__ __launch_bounds__(256) void k1b_gemm(
    const float* __restrict__ h_seq, const float* __restrict__ Wt,
    const float* __restrict__ b_ih, float* __restrict__ xg)
{
  __shared__ __align__(16) float Ws[64 * 60];    // 15 KB, f-major chunk
  const int bid = blockIdx.x;
  const int b = bid >> 4;
  const int t0 = (bid & 15) << 6;          // 16 t-chunks of 64 rows
  const int tid = threadIdx.x;
  const int rg = tid >> 4;                 // 0..15 -> rows rg*4..rg*4+3
  const int gcol = tid & 15;               // 0..15 -> gates gcol*4..+3
  const int gc4 = (gcol < 15) ? gcol * 4 : 56;   // clamp col 15 (dup of 14)
  const float* hsb = h_seq + ((size_t)b * T_ + t0) * HS_;

  float acc[4][4];
  #pragma unroll
  for (int i = 0; i < 4; ++i)
    #pragma unroll
    for (int j = 0; j < 4; ++j) acc[i][j] = 0.f;

  for (int c = 0; c < 4; ++c) {            // f-chunks of 64
    const int FC = c * 64;
    __syncthreads();                       // Ws readers of chunk c-1 done
    for (int j = tid; j < 64 * 60; j += 256)
      Ws[j] = Wt[(size_t)FC * G_ + j];
    __syncthreads();
    #pragma unroll
    for (int fj = 0; fj < 16; ++fj) {
      const float* wp = &Ws[(fj * 4) * 60 + gc4];
      const float4 w0 = *(const float4*)(wp);
      const float4 w1 = *(const float4*)(wp + 60);
      const float4 w2 = *(const float4*)(wp + 120);
      const float4 w3 = *(const float4*)(wp + 180);
      #pragma unroll
      for (int i = 0; i < 4; ++i) {
        const int row = (rg << 2) + i;
        const float4 a4 =
            *(const float4*)&hsb[(size_t)row * HS_ + FC + fj * 4];
        acc[i][0] = fmaf(a4.x, w0.x, fmaf(a4.y, w1.x, fmaf(a4.z, w2.x, fmaf(a4.w, w3.x, acc[i][0]))));
        acc[i][1] = fmaf(a4.x, w0.y, fmaf(a4.y, w1.y, fmaf(a4.z, w2.y, fmaf(a4.w, w3.y, acc[i][1]))));
        acc[i][2] = fmaf(a4.x, w0.z, fmaf(a4.y, w1.z, fmaf(a4.z, w2.z, fmaf(a4.w, w3.z, acc[i][2]))));
        acc[i][3] = fmaf(a4.x, w0.w, fmaf(a4.y, w1.w, fmaf(a4.z, w2.w, fmaf(a4.w, w3.w, acc[i][3]))));
      }
    }
  }

  if (gcol < 15) {
    const float4 bi4 = *(const float4*)&b_ih[gc4];
    #pragma unroll
    for (int i = 0; i < 4; ++i) {
      const int row = (rg << 2) + i;
      float4 o;
      o.x = acc[i][0] + bi4.x;  o.y = acc[i][1] + bi4.y;
      o.z = acc[i][2] + bi4.z;  o.w = acc[i][3] + bi4.w;
      *(float4*)&xg[((size_t)b * T_ + t0 + row) * G_ + gc4] = o;
    }
  }
}

// ---------------- K2: fused recurrence(x2) + decoder + loss ----------------
// Block = TWO batch rows, 9 waves. Wave 0 runs BOTH rows' recurrences in one
// wave: each lane computes gate j for chain A (row 2b) and chain B (row 2b+1)
// back-to-back; the two dependence chains are independent, so their
// instruction streams interleave and fill each other's stalls (r14 evidence:
// single-chain step = ~470cy vs ~160cy issue floor -> ~300cy stalls/step).
// Weights are shared (no duplication); only es-SGPR sets, prefetch arrays,
// and temps double. Waves 1-8 decode: thread = (row, column f); same
// per-thread workload and barrier pattern as the validated r14 kernel.
__global__ __launch_bounds__(576) void k2_fused(
    const float* __restrict__ e0, const float* __restrict__ W_hh,
    const float* __restrict__ b_hh, const float* __restrict__ xg,
    const float* __restrict__ h_seq, const float* __restrict__ W_dec,
    const float* __restrict__ b_dec, float* __restrict__ partials)
{
  __shared__ float ebuf[2][2][P_][H_];   // [pingpong][row][step][j], 2560 B
  __shared__ float red[12];
  const int b = blockIdx.x;              // 0..63 -> rows 2b, 2b+1
  const int tid = threadIdx.x;
  const int lane = tid & 63;
  const int wave = tid >> 6;
  float acc = 0.f;   // producer wave leaves 0

  if (wave == 0) {
    // ---------------- producer: dual recurrence ----------------
    const bool own = lane < H_;
    const int j0 = own ? lane : 0;

    float2 wr2[10], wz2[10], wn2[10];
    #pragma unroll
    for (int k = 0; k < 10; ++k) {
      const float2 a = *(const float2*)&W_hh[j0 * H_ + 2 * k];
      const float2 c = *(const float2*)&W_hh[(j0 + 20) * H_ + 2 * k];
      const float2 d = *(const float2*)&W_hh[(j0 + 40) * H_ + 2 * k];
      wr2[k] = make_float2(a.x * NL2E_, a.y * NL2E_);
      wz2[k] = make_float2(c.x * NL2E_, c.y * NL2E_);
      wn2[k] = make_float2(d.x * L2E2_, d.y * L2E2_);
    }
    const float bhr = b_hh[j0] * NL2E_;
    const float bhz = b_hh[j0 + 20] * NL2E_;
    const float bhn = b_hh[j0 + 40] * L2E2_;

    float eA = e0[(2 * b) * H_ + j0];
    float eB = e0[(2 * b + 1) * H_ + j0];
    float2 esA[10], esB[10];
    #pragma unroll
    for (int k = 0; k < 10; ++k) {
      esA[k].x = rdlane(eA, 2 * k);  esA[k].y = rdlane(eA, 2 * k + 1);
      esB[k].x = rdlane(eB, 2 * k);  esB[k].y = rdlane(eB, 2 * k + 1);
    }

    const float* xgbA = xg + (size_t)(2 * b) * T_ * G_;
    const float* xgbB = xg + (size_t)(2 * b + 1) * T_ * G_;
    float xrA[P_], xzA[P_], xnA[P_], xrB[P_], xzB[P_], xnB[P_];
    #pragma unroll
    for (int j = 0; j < P_; ++j) {
      xrA[j] = xgbA[(size_t)j * G_ + j0] * NL2E_;
      xzA[j] = xgbA[(size_t)j * G_ + j0 + 20] * NL2E_;
      xnA[j] = xgbA[(size_t)j * G_ + j0 + 40] * L2E2_;
      xrB[j] = xgbB[(size_t)j * G_ + j0] * NL2E_;
      xzB[j] = xgbB[(size_t)j * G_ + j0 + 20] * NL2E_;
      xnB[j] = xgbB[(size_t)j * G_ + j0 + 40] * L2E2_;
    }

#define STEP(j, RELOAD)                                                    \
    {                                                                      \
      const int t = t0 + (j);                                              \
      const float xrvA = xrA[j], xzvA = xzA[j], xnvA = xnA[j];             \
      const float xrvB = xrB[j], xzvB = xzB[j], xnvB = xnB[j];             \
      if (RELOAD) {                                                        \
        const float* xpA = xgbA + (size_t)(t + P_) * G_;                   \
        const float* xpB = xgbB + (size_t)(t + P_) * G_;                   \
        xrA[j] = xpA[j0] * NL2E_;       xrB[j] = xpB[j0] * NL2E_;          \
        xzA[j] = xpA[j0 + 20] * NL2E_;  xzB[j] = xpB[j0 + 20] * NL2E_;     \
        xnA[j] = xpA[j0 + 40] * L2E2_;  xnB[j] = xpB[j0 + 40] * L2E2_;     \
      }                                                                    \
      float2 r0A = make_float2(bhr, 0.f), r1A = make_float2(0.f, 0.f);     \
      float2 z0A = make_float2(bhz, 0.f), z1A = make_float2(0.f, 0.f);     \
      float2 n0A = make_float2(bhn, 0.f), n1A = make_float2(0.f, 0.f);     \
      float2 r0B = make_float2(bhr, 0.f), r1B = make_float2(0.f, 0.f);     \
      float2 z0B = make_float2(bhz, 0.f), z1B = make_float2(0.f, 0.f);     \
      float2 n0B = make_float2(bhn, 0.f), n1B = make_float2(0.f, 0.f);     \
      _Pragma("unroll")                                                    \
      for (int k = 0; k < 5; ++k) {                                        \
        r0A = wr2[k] * esA[k] + r0A;  r0B = wr2[k] * esB[k] + r0B;         \
        r1A = wr2[k + 5] * esA[k + 5] + r1A;                               \
        r1B = wr2[k + 5] * esB[k + 5] + r1B;                               \
        z0A = wz2[k] * esA[k] + z0A;  z0B = wz2[k] * esB[k] + z0B;         \
        z1A = wz2[k + 5] * esA[k + 5] + z1A;                               \
        z1B = wz2[k + 5] * esB[k + 5] + z1B;                               \
        n0A = wn2[k] * esA[k] + n0A;  n0B = wn2[k] * esB[k] + n0B;         \
        n1A = wn2[k + 5] * esA[k + 5] + n1A;                               \
        n1B = wn2[k + 5] * esB[k + 5] + n1B;                               \
      }                                                                    \
      const float hrA = (r0A.x + r1A.x) + (r0A.y + r1A.y);                 \
      const float hrB = (r0B.x + r1B.x) + (r0B.y + r1B.y);                 \
      const float hzA = (z0A.x + z1A.x) + (z0A.y + z1A.y);                 \
      const float hzB = (z0B.x + z1B.x) + (z0B.y + z1B.y);                 \
      const float hnA = (n0A.x + n1A.x) + (n0A.y + n1A.y);                 \
      const float hnB = (n0B.x + n1B.x) + (n0B.y + n1B.y);                 \
      const float rgA = RCP(1.f + EXP2(xrvA + hrA));                       \
      const float rgB = RCP(1.f + EXP2(xrvB + hrB));                       \
      const float zgA = RCP(1.f + EXP2(xzvA + hzA));                       \
      const float zgB = RCP(1.f + EXP2(xzvB + hzB));                       \
      const float aaA = fmaf(rgA, hnA, xnvA);                              \
      const float aaB = fmaf(rgB, hnB, xnvB);                              \
      const float ngA = fmaf(-2.f, RCP(EXP2(aaA) + 1.f), 1.f);             \
      const float ngB = fmaf(-2.f, RCP(EXP2(aaB) + 1.f), 1.f);             \
      const float enA = fmaf(zgA, eA - ngA, ngA);                          \
      const float enB = fmaf(zgB, eB - ngB, ngB);                          \
      if (own) {                                                           \
        ebuf[(t0 >> 3) & 1][0][j][lane] = enA;                             \
        ebuf[(t0 >> 3) & 1][1][j][lane] = enB;                             \
      }                                                                    \
      eA = enA;  eB = enB;                                                 \
      _Pragma("unroll")                                                    \
      for (int k = 0; k < 10; ++k) {                                       \
        esA[k].x = rdlane(enA, 2 * k);  esA[k].y = rdlane(enA, 2 * k + 1); \
        esB[k].x = rdlane(enB, 2 * k);  esB[k].y = rdlane(enB, 2 * k + 1); \
      }                                                                    \
    }

    for (int t0 = 0; t0 < T_ - P_; t0 += P_) {
      STEP(0, true) STEP(1, true) STEP(2, true) STEP(3, true)
      STEP(4, true) STEP(5, true) STEP(6, true) STEP(7, true)
      __syncthreads();                 // publish group t0/8
    }
    {
      const int t0 = T_ - P_;
      STEP(0, false) STEP(1, false) STEP(2, false) STEP(3, false)
      STEP(4, false) STEP(5, false) STEP(6, false) STEP(7, false)
      __syncthreads();                 // publish last group
    }
#undef STEP
  } else {
    // ---------------- consumers: decoder + squared error (8 waves, 2 rows) ----
    const int ct = tid - 64;           // 0..511
    const int row = ct >> 8;           // 0 or 1
    const int f0 = ct & 255;
    const bool act = f0 < F_;
    const int f = act ? f0 : 0;
    float wd[H_];
    #pragma unroll
    for (int k = 0; k < H_; ++k) wd[k] = W_dec[f * H_ + k];
    const float bd = b_dec[f];
    const float* hsb = h_seq + (size_t)(2 * b + row) * T_ * HS_;

    float hcur[P_], hnxt[P_];
    #pragma unroll
    for (int j = 0; j < P_; ++j) hcur[j] = hsb[(size_t)j * HS_ + f];

    for (int g = 0; g < T_ / P_; ++g) {
      __syncthreads();                 // ebuf group g published
      if (g < T_ / P_ - 1) {
        #pragma unroll
        for (int j = 0; j < P_; ++j)
          hnxt[j] = hsb[(size_t)(P_ * (g + 1) + j) * HS_ + f];
      }
      const float* eb = &ebuf[g & 1][row][0][0];
      #pragma unroll
      for (int j = 0; j < P_; ++j) {
        const float2* ep = (const float2*)&eb[j * H_];
        float d = bd;
        #pragma unroll
        for (int k = 0; k < 10; ++k) {
          const float2 e2 = ep[k];
          d = fmaf(wd[2 * k], e2.x, fmaf(wd[2 * k + 1], e2.y, d));
        }
        const float fo = fmaxf(d, 0.f);
        const float df = fo - hcur[j];
        if (act) acc = fmaf(df, df, acc);
      }
      #pragma unroll
      for (int j = 0; j < P_; ++j) hcur[j] = hnxt[j];
    }
  }

  // deterministic block reduction (producer contributes 0)
  #pragma unroll
  for (int m = 32; m >= 1; m >>= 1) acc += __shfl_xor(acc, m);
  if (lane == 0) red[wave] = acc;
  __syncthreads();
  if (tid == 0) {
    float s = red[0];
    #pragma unroll
    for (int w = 1; w < 9; ++w) s += red[w];
    partials[b] = s;
  }
}

// ---------------- K3: final deterministic reduction over 64 partials ----------------
__global__ __launch_bounds__(64) void k3_reduce(
    const float* __restrict__ partials, float* __restrict__ out)
{
  const int lane = threadIdx.x;
  float a = partials[lane];
  #pragma unroll
  for (int m = 32; m >= 1; m >>= 1) a += __shfl_xor(a, m);
  if (lane == 0) out[0] = a * (float)(1.0 / ((double)T_ * B_ * F_));
}

extern "C" void kernel_launch(void* const* d_in, const int* in_sizes, int n_in,
                              void* d_out, int out_size, void* d_ws, size_t ws_size,
                              hipStream_t stream) {
  const float* feats = (const float*)d_in[0];
  const float* e0    = (const float*)d_in[1];
  const float* W_ih  = (const float*)d_in[2];
  const float* W_hh  = (const float*)d_in[3];
  const float* b_ih  = (const float*)d_in[4];
  const float* b_hh  = (const float*)d_in[5];
  const float* W_dec = (const float*)d_in[6];
  const float* b_dec = (const float*)d_in[7];
  float* out = (float*)d_out;

  float* ws = (float*)d_ws;
  float* h_seq    = ws;                                    // B*T*HS_ floats (b-major, padded)
  float* xgates   = ws + (size_t)B_ * T_ * HS_;            // B*T*G floats (b-major)
  float* partials = xgates + (size_t)B_ * T_ * G_;         // 64 floats
  float* Wt       = partials + 128;                        // FP_*G_ floats

  hipLaunchKernelGGL(k1a_pool, dim3(T_ * (B_ / 8)), dim3(256), 0, stream,
                     feats, h_seq, W_ih, Wt);
  hipLaunchKernelGGL(k1b_gemm, dim3(B_ * 16), dim3(256), 0, stream,
                     h_seq, Wt, b_ih, xgates);
  hipLaunchKernelGGL(k2_fused, dim3(B_ / 2), dim3(576), 0, stream,
                     e0, W_hh, b_hh, xgates, h_seq, W_dec, b_dec, partials);
  hipLaunchKernelGGL(k3_reduce, dim3(1), dim3(64), 0, stream,
                     partials, out);
}

// Round 18
// 501.612 us; speedup vs baseline: 1.2328x; 1.2328x over previous
//
#include <hip/hip_runtime.h>
#include <cstddef>

#define T_ 1024
#define B_ 128
#define F_ 243
#define H_ 20
#define G_ 60   // 3*H
#define R_ 512  // B*POOL
#define P_ 8    // xg prefetch depth / e-group size in k2
#define FP_ 256 // padded F for Wt (f-major transposed W_ih)
#define HS_ 244 // h_seq row stride: 244 floats = 976 B -> 16-B aligned rows

__device__ __forceinline__ float bperm(int addr, float v) {
  return __int_as_float(__builtin_amdgcn_ds_bpermute(addr, __float_as_int(v)));
}
#define RCP(x) __builtin_amdgcn_rcpf(x)
#if __has_builtin(__builtin_amdgcn_exp2f)
#define EXP2(x) __builtin_amdgcn_exp2f(x)
#else
#define EXP2(x) __expf((x) * 0.6931471805599453f)
#endif
#define NL2E_ -1.4426950408889634f   // -log2(e)
#define L2E2_ 2.8853900817779268f    // 2*log2(e)

// ---------------- K1a: streaming max-pool(4): feats -> h_seq (b-major, stride 244) -------
// Unchanged (validated r7-r16). Blocks 0..59 also build Wt[256][60].
__global__ __launch_bounds__(256) void k1a_pool(
    const float* __restrict__ feats, float* __restrict__ h_seq,
    const float* __restrict__ W_ih, float* __restrict__ Wt)
{
  const int bid = blockIdx.x;           // 16384 = 1024 t x 16 b-groups
  if (bid < 60) {                       // folded k0: 60*256 >= FP_*G_
    const int i = bid * 256 + threadIdx.x;
    if (i < FP_ * G_) {
      const int f = i / G_, g = i - f * G_;
      Wt[(size_t)f * G_ + g] = (f < F_) ? W_ih[(size_t)g * F_ + f] : 0.f;
    }
  }
  const int t = bid & (T_ - 1);
  const int b0 = (bid >> 10) << 3;      // 8 batch rows per block
  const int col = threadIdx.x;
  if (col < F_) {
    #pragma unroll
    for (int bb = 0; bb < 8; ++bb) {
      const float* p =
          feats + ((size_t)t * R_ + (size_t)(b0 + bb) * 4) * F_ + col;
      const float v =
          fmaxf(fmaxf(p[0], p[F_]), fmaxf(p[2 * F_], p[3 * F_]));
      h_seq[((size_t)(b0 + bb) * T_ + t) * HS_ + col] = v;
    }
  }
}

// ---------------- K1b: GEMM  xg = h_seq @ W_ih^T + b_ih  (unchanged, validated) ----------
__global__ __launch_bounds__(256) void k1b_gemm(
    const float* __restrict__ h_seq, const float* __restrict__ Wt,
    const float* __restrict__ b_ih, float* __restrict__ xg)
{
  __shared__ __align__(16) float Ws[64 * 60];    // 15 KB, f-major chunk
  const int bid = blockIdx.x;
  const int b = bid >> 4;
  const int t0 = (bid & 15) << 6;          // 16 t-chunks of 64 rows
  const int tid = threadIdx.x;
  const int rg = tid >> 4;                 // 0..15 -> rows rg*4..rg*4+3
  const int gcol = tid & 15;               // 0..15 -> gates gcol*4..+3
  const int gc4 = (gcol < 15) ? gcol * 4 : 56;   // clamp col 15 (dup of 14)
  const float* hsb = h_seq + ((size_t)b * T_ + t0) * HS_;

  float acc[4][4];
  #pragma unroll
  for (int i = 0; i < 4; ++i)
    #pragma unroll
    for (int j = 0; j < 4; ++j) acc[i][j] = 0.f;

  for (int c = 0; c < 4; ++c) {            // f-chunks of 64
    const int FC = c * 64;
    __syncthreads();                       // Ws readers of chunk c-1 done
    for (int j = tid; j < 64 * 60; j += 256)
      Ws[j] = Wt[(size_t)FC * G_ + j];
    __syncthreads();
    #pragma unroll
    for (int fj = 0; fj < 16; ++fj) {
      const float* wp = &Ws[(fj * 4) * 60 + gc4];
      const float4 w0 = *(const float4*)(wp);
      const float4 w1 = *(const float4*)(wp + 60);
      const float4 w2 = *(const float4*)(wp + 120);
      const float4 w3 = *(const float4*)(wp + 180);
      #pragma unroll
      for (int i = 0; i < 4; ++i) {
        const int row = (rg << 2) + i;
        const float4 a4 =
            *(const float4*)&hsb[(size_t)row * HS_ + FC + fj * 4];
        acc[i][0] = fmaf(a4.x, w0.x, fmaf(a4.y, w1.x, fmaf(a4.z, w2.x, fmaf(a4.w, w3.x, acc[i][0]))));
        acc[i][1] = fmaf(a4.x, w0.y, fmaf(a4.y, w1.y, fmaf(a4.z, w2.y, fmaf(a4.w, w3.y, acc[i][1]))));
        acc[i][2] = fmaf(a4.x, w0.z, fmaf(a4.y, w1.z, fmaf(a4.z, w2.z, fmaf(a4.w, w3.z, acc[i][2]))));
        acc[i][3] = fmaf(a4.x, w0.w, fmaf(a4.y, w1.w, fmaf(a4.z, w2.w, fmaf(a4.w, w3.w, acc[i][3]))));
      }
    }
  }

  if (gcol < 15) {
    const float4 bi4 = *(const float4*)&b_ih[gc4];
    #pragma unroll
    for (int i = 0; i < 4; ++i) {
      const int row = (rg << 2) + i;
      float4 o;
      o.x = acc[i][0] + bi4.x;  o.y = acc[i][1] + bi4.y;
      o.z = acc[i][2] + bi4.z;  o.w = acc[i][3] + bi4.w;
      *(float4*)&xg[((size_t)b * T_ + t0 + row) * G_ + gc4] = o;
    }
  }
}

// ---------------- K2: fused recurrence(x2, SPLIT LANES) + decoder + loss ----------------
// Block = TWO batch rows, 9 waves. Wave 0 runs both rows' recurrences with ONE
// instruction stream: lanes 0-19 = row 2b, lanes 32-51 = row 2b+1 (r17 lesson:
// same-lane software interleave doubles issue; SIMD lane-split does not).
// The e broadcast uses ds_bpermute with precomputed per-half indices
// (src = (lane&32)|k), replacing the wave-wide readlane/SGPR scheme.
// Waves 1-8 = r17's validated consumers (thread = (row, column f)).
__global__ __launch_bounds__(576) void k2_fused(
    const float* __restrict__ e0, const float* __restrict__ W_hh,
    const float* __restrict__ b_hh, const float* __restrict__ xg,
    const float* __restrict__ h_seq, const float* __restrict__ W_dec,
    const float* __restrict__ b_dec, float* __restrict__ partials)
{
  __shared__ float ebuf[2][2][P_][H_];   // [pingpong][row][step][j], 2560 B
  __shared__ float red[12];
  const int b = blockIdx.x;              // 0..63 -> rows 2b, 2b+1
  const int tid = threadIdx.x;
  const int lane = tid & 63;
  const int wave = tid >> 6;
  float acc = 0.f;   // producer wave leaves 0

  if (wave == 0) {
    // ---------------- producer: dual recurrence in split lanes ----------------
    const int half = lane >> 5;          // 0 = row 2b, 1 = row 2b+1
    const int li = lane & 31;
    const bool own = li < H_;
    const int j0 = own ? li : 0;
    const int row = 2 * b + half;

    int bidx[H_];                        // bpermute byte-addr: src lane (half*32)|k
    #pragma unroll
    for (int k = 0; k < H_; ++k) bidx[k] = ((lane & 32) | k) << 2;

    float2 wr2[10], wz2[10], wn2[10];
    #pragma unroll
    for (int k = 0; k < 10; ++k) {
      const float2 a = *(const float2*)&W_hh[j0 * H_ + 2 * k];
      const float2 c = *(const float2*)&W_hh[(j0 + 20) * H_ + 2 * k];
      const float2 d = *(const float2*)&W_hh[(j0 + 40) * H_ + 2 * k];
      wr2[k] = make_float2(a.x * NL2E_, a.y * NL2E_);
      wz2[k] = make_float2(c.x * NL2E_, c.y * NL2E_);
      wn2[k] = make_float2(d.x * L2E2_, d.y * L2E2_);
    }
    const float bhr = b_hh[j0] * NL2E_;
    const float bhz = b_hh[j0 + 20] * NL2E_;
    const float bhn = b_hh[j0 + 40] * L2E2_;

    float e_own = e0[row * H_ + j0];
    float2 es2[10];
    #pragma unroll
    for (int k = 0; k < 10; ++k) {
      es2[k].x = bperm(bidx[2 * k], e_own);
      es2[k].y = bperm(bidx[2 * k + 1], e_own);
    }

    const float* xgb = xg + (size_t)row * T_ * G_;   // per-lane (row differs by half)
    float xr[P_], xz[P_], xn[P_];
    #pragma unroll
    for (int j = 0; j < P_; ++j) {
      xr[j] = xgb[(size_t)j * G_ + j0] * NL2E_;
      xz[j] = xgb[(size_t)j * G_ + j0 + 20] * NL2E_;
      xn[j] = xgb[(size_t)j * G_ + j0 + 40] * L2E2_;
    }

#define STEP(j, RELOAD)                                                    \
    {                                                                      \
      const int t = t0 + (j);                                              \
      const float xrv = xr[j], xzv = xz[j], xnv = xn[j];                   \
      if (RELOAD) {                                                        \
        const float* xp = xgb + (size_t)(t + P_) * G_;                     \
        xr[j] = xp[j0] * NL2E_;                                            \
        xz[j] = xp[j0 + 20] * NL2E_;                                       \
        xn[j] = xp[j0 + 40] * L2E2_;                                       \
      }                                                                    \
      float2 rA = make_float2(bhr, 0.f), rB = make_float2(0.f, 0.f);       \
      float2 zA = make_float2(bhz, 0.f), zB = make_float2(0.f, 0.f);       \
      float2 nA = make_float2(bhn, 0.f), nB = make_float2(0.f, 0.f);       \
      _Pragma("unroll")                                                    \
      for (int k = 0; k < 5; ++k) {                                        \
        rA = wr2[k] * es2[k] + rA;   rB = wr2[k + 5] * es2[k + 5] + rB;    \
        zA = wz2[k] * es2[k] + zA;   zB = wz2[k + 5] * es2[k + 5] + zB;    \
        nA = wn2[k] * es2[k] + nA;   nB = wn2[k + 5] * es2[k + 5] + nB;    \
      }                                                                    \
      const float hr2 = (rA.x + rB.x) + (rA.y + rB.y);                     \
      const float hz2 = (zA.x + zB.x) + (zA.y + zB.y);                     \
      const float hn2 = (nA.x + nB.x) + (nA.y + nB.y);                     \
      const float rg = RCP(1.f + EXP2(xrv + hr2));                         \
      const float zg = RCP(1.f + EXP2(xzv + hz2));                         \
      const float aa2 = fmaf(rg, hn2, xnv);                                \
      const float ng = fmaf(-2.f, RCP(EXP2(aa2) + 1.f), 1.f);              \
      const float enew = fmaf(zg, e_own - ng, ng);                         \
      if (own) ebuf[(t0 >> 3) & 1][half][j][li] = enew;                    \
      e_own = enew;                                                        \
      _Pragma("unroll")                                                    \
      for (int k = 0; k < 10; ++k) {                                       \
        es2[k].x = bperm(bidx[2 * k], enew);                               \
        es2[k].y = bperm(bidx[2 * k + 1], enew);                           \
      }                                                                    \
    }

    for (int t0 = 0; t0 < T_ - P_; t0 += P_) {
      STEP(0, true) STEP(1, true) STEP(2, true) STEP(3, true)
      STEP(4, true) STEP(5, true) STEP(6, true) STEP(7, true)
      __syncthreads();                 // publish group t0/8
    }
    {
      const int t0 = T_ - P_;
      STEP(0, false) STEP(1, false) STEP(2, false) STEP(3, false)
      STEP(4, false) STEP(5, false) STEP(6, false) STEP(7, false)
      __syncthreads();                 // publish last group
    }
#undef STEP
  } else {
    // ---------------- consumers: decoder + squared error (8 waves, 2 rows) ----
    const int ct = tid - 64;           // 0..511
    const int row = ct >> 8;           // 0 or 1
    const int f0 = ct & 255;
    const bool act = f0 < F_;
    const int f = act ? f0 : 0;
    float wd[H_];
    #pragma unroll
    for (int k = 0; k < H_; ++k) wd[k] = W_dec[f * H_ + k];
    const float bd = b_dec[f];
    const float* hsb = h_seq + (size_t)(2 * b + row) * T_ * HS_;

    float hcur[P_], hnxt[P_];
    #pragma unroll
    for (int j = 0; j < P_; ++j) hcur[j] = hsb[(size_t)j * HS_ + f];

    for (int g = 0; g < T_ / P_; ++g) {
      __syncthreads();                 // ebuf group g published
      if (g < T_ / P_ - 1) {
        #pragma unroll
        for (int j = 0; j < P_; ++j)
          hnxt[j] = hsb[(size_t)(P_ * (g + 1) + j) * HS_ + f];
      }
      const float* eb = &ebuf[g & 1][row][0][0];
      #pragma unroll
      for (int j = 0; j < P_; ++j) {
        const float2* ep = (const float2*)&eb[j * H_];
        float d = bd;
        #pragma unroll
        for (int k = 0; k < 10; ++k) {
          const float2 e2 = ep[k];
          d = fmaf(wd[2 * k], e2.x, fmaf(wd[2 * k + 1], e2.y, d));
        }
        const float fo = fmaxf(d, 0.f);
        const float df = fo - hcur[j];
        if (act) acc = fmaf(df, df, acc);
      }
      #pragma unroll
      for (int j = 0; j < P_; ++j) hcur[j] = hnxt[j];
    }
  }

  // deterministic block reduction (producer contributes 0)
  #pragma unroll
  for (int m = 32; m >= 1; m >>= 1) acc += __shfl_xor(acc, m);
  if (lane == 0) red[wave] = acc;
  __syncthreads();
  if (tid == 0) {
    float s = red[0];
    #pragma unroll
    for (int w = 1; w < 9; ++w) s += red[w];
    partials[b] = s;
  }
}

// ---------------- K3: final deterministic reduction over 64 partials ----------------
__global__ __launch_bounds__(64) void k3_reduce(
    const float* __restrict__ partials, float* __restrict__ out)
{
  const int lane = threadIdx.x;
  float a = partials[lane];
  #pragma unroll
  for (int m = 32; m >= 1; m >>= 1) a += __shfl_xor(a, m);
  if (lane == 0) out[0] = a * (float)(1.0 / ((double)T_ * B_ * F_));
}

extern "C" void kernel_launch(void* const* d_in, const int* in_sizes, int n_in,
                              void* d_out, int out_size, void* d_ws, size_t ws_size,
                              hipStream_t stream) {
  const float* feats = (const float*)d_in[0];
  const float* e0    = (const float*)d_in[1];
  const float* W_ih  = (const float*)d_in[2];
  const float* W_hh  = (const float*)d_in[3];
  const float* b_ih  = (const float*)d_in[4];
  const float* b_hh  = (const float*)d_in[5];
  const float* W_dec = (const float*)d_in[6];
  const float* b_dec = (const float*)d_in[7];
  float* out = (float*)d_out;

  float* ws = (float*)d_ws;
  float* h_seq    = ws;                                    // B*T*HS_ floats (b-major, padded)
  float* xgates   = ws + (size_t)B_ * T_ * HS_;            // B*T*G floats (b-major)
  float* partials = xgates + (size_t)B_ * T_ * G_;         // 64 floats
  float* Wt       = partials + 128;                        // FP_*G_ floats

  hipLaunchKernelGGL(k1a_pool, dim3(T_ * (B_ / 8)), dim3(256), 0, stream,
                     feats, h_seq, W_ih, Wt);
  hipLaunchKernelGGL(k1b_gemm, dim3(B_ * 16), dim3(256), 0, stream,
                     h_seq, Wt, b_ih, xgates);
  hipLaunchKernelGGL(k2_fused, dim3(B_ / 2), dim3(576), 0, stream,
                     e0, W_hh, b_hh, xgates, h_seq, W_dec, b_dec, partials);
  hipLaunchKernelGGL(k3_reduce, dim3(1), dim3(64), 0, stream,
                     partials, out);
}

// Round 19
// 446.296 us; speedup vs baseline: 1.3856x; 1.1239x over previous
//
#include <hip/hip_runtime.h>
#include <cstddef>

#define T_ 1024
#define B_ 128
#define F_ 243
#define H_ 20
#define G_ 60   // 3*H
#define R_ 512  // B*POOL
#define P_ 8    // xg prefetch depth / e-group size in k2
#define FP_ 256 // padded F for Wt (f-major transposed W_ih)
#define HS_ 244 // h_seq row stride: 244 floats = 976 B -> 16-B aligned rows

__device__ __forceinline__ float rdlane(float v, int l) {
  return __int_as_float(__builtin_amdgcn_readlane(__float_as_int(v), l));
}
#define RCP(x) __builtin_amdgcn_rcpf(x)
#if __has_builtin(__builtin_amdgcn_exp2f)
#define EXP2(x) __builtin_amdgcn_exp2f(x)
#else
#define EXP2(x) __expf((x) * 0.6931471805599453f)
#endif
#define NL2E_ -1.4426950408889634f   // -log2(e)
#define L2E2_ 2.8853900817779268f    // 2*log2(e)

// ---------------- K1a: streaming max-pool(4): feats -> h_seq (b-major, stride 244) -------
// Fully contiguous 972-B reads/writes, no LDS, no barriers (validated r7-r16).
// Blocks 0..59 additionally build Wt[256][60] (f-major transpose of W_ih,
// rows f>=243 zero); k1b launches after k1a so Wt is complete when consumed.
__global__ __launch_bounds__(256) void k1a_pool(
    const float* __restrict__ feats, float* __restrict__ h_seq,
    const float* __restrict__ W_ih, float* __restrict__ Wt)
{
  const int bid = blockIdx.x;           // 16384 = 1024 t x 16 b-groups
  if (bid < 60) {                       // folded k0: 60*256 >= FP_*G_
    const int i = bid * 256 + threadIdx.x;
    if (i < FP_ * G_) {
      const int f = i / G_, g = i - f * G_;
      Wt[(size_t)f * G_ + g] = (f < F_) ? W_ih[(size_t)g * F_ + f] : 0.f;
    }
  }
  const int t = bid & (T_ - 1);
  const int b0 = (bid >> 10) << 3;      // 8 batch rows per block
  const int col = threadIdx.x;
  if (col < F_) {
    #pragma unroll
    for (int bb = 0; bb < 8; ++bb) {
      const float* p =
          feats + ((size_t)t * R_ + (size_t)(b0 + bb) * 4) * F_ + col;
      const float v =
          fmaxf(fmaxf(p[0], p[F_]), fmaxf(p[2 * F_], p[3 * F_]));
      h_seq[((size_t)(b0 + bb) * T_ + t) * HS_ + col] = v;
    }
  }
}

// ---------------- K1b: GEMM  xg = h_seq @ W_ih^T + b_ih  (r11/r13 version, validated) ----
// A read directly from global (16 lanes of a rg-group load the SAME float4;
// coalescer collapses, L1-resident), consumed immediately -> no spills. Only
// Ws (15 KB/chunk) in LDS. 64-row blocks (grid 2048) so one block's Ws-stage
// barriers hide under other blocks' FMA phases. Output: [b][t][G] float4s.
// NOTE (r15 lesson): these A loads are hidden by multi-block TLP; moving this
// GEMM onto k2's barrier-locked critical path serializes the latency (3x).
__global__ __launch_bounds__(256) void k1b_gemm(
    const float* __restrict__ h_seq, const float* __restrict__ Wt,
    const float* __restrict__ b_ih, float* __restrict__ xg)
{
  __shared__ __align__(16) float Ws[64 * 60];    // 15 KB, f-major chunk
  const int bid = blockIdx.x;
  const int b = bid >> 4;
  const int t0 = (bid & 15) << 6;          // 16 t-chunks of 64 rows
  const int tid = threadIdx.x;
  const int rg = tid >> 4;                 // 0..15 -> rows rg*4..rg*4+3
  const int gcol = tid & 15;               // 0..15 -> gates gcol*4..+3
  const int gc4 = (gcol < 15) ? gcol * 4 : 56;   // clamp col 15 (dup of 14)
  const float* hsb = h_seq + ((size_t)b * T_ + t0) * HS_;

  float acc[4][4];
  #pragma unroll
  for (int i = 0; i < 4; ++i)
    #pragma unroll
    for (int j = 0; j < 4; ++j) acc[i][j] = 0.f;

  for (int c = 0; c < 4; ++c) {            // f-chunks of 64
    const int FC = c * 64;
    __syncthreads();                       // Ws readers of chunk c-1 done
    for (int j = tid; j < 64 * 60; j += 256)
      Ws[j] = Wt[(size_t)FC * G_ + j];
    __syncthreads();
    #pragma unroll
    for (int fj = 0; fj < 16; ++fj) {
      const float* wp = &Ws[(fj * 4) * 60 + gc4];
      const float4 w0 = *(const float4*)(wp);
      const float4 w1 = *(const float4*)(wp + 60);
      const float4 w2 = *(const float4*)(wp + 120);
      const float4 w3 = *(const float4*)(wp + 180);
      #pragma unroll
      for (int i = 0; i < 4; ++i) {
        const int row = (rg << 2) + i;
        const float4 a4 =
            *(const float4*)&hsb[(size_t)row * HS_ + FC + fj * 4];
        acc[i][0] = fmaf(a4.x, w0.x, fmaf(a4.y, w1.x, fmaf(a4.z, w2.x, fmaf(a4.w, w3.x, acc[i][0]))));
        acc[i][1] = fmaf(a4.x, w0.y, fmaf(a4.y, w1.y, fmaf(a4.z, w2.y, fmaf(a4.w, w3.y, acc[i][1]))));
        acc[i][2] = fmaf(a4.x, w0.z, fmaf(a4.y, w1.z, fmaf(a4.z, w2.z, fmaf(a4.w, w3.z, acc[i][2]))));
        acc[i][3] = fmaf(a4.x, w0.w, fmaf(a4.y, w1.w, fmaf(a4.z, w2.w, fmaf(a4.w, w3.w, acc[i][3]))));
      }
    }
  }

  if (gcol < 15) {
    const float4 bi4 = *(const float4*)&b_ih[gc4];
    #pragma unroll
    for (int i = 0; i < 4; ++i) {
      const int row = (rg << 2) + i;
      float4 o;
      o.x = acc[i][0] + bi4.x;  o.y = acc[i][1] + bi4.y;
      o.z = acc[i][2] + bi4.z;  o.w = acc[i][3] + bi4.w;
      *(float4*)&xg[((size_t)b * T_ + t0 + row) * G_ + gc4] = o;
    }
  }
}

// ---------------- K2: fused recurrence + decoder + loss (r14/r16, validated 444 us) ------
// 5 waves per block, one block per batch row. Wave 0 = register recurrence
// (lane j<20 owns gate triple; e broadcast via readlane -- measured cheapest
// cross-lane primitive: bpermute variant (r18) cost +50cy/step on the chain;
// 3 dword xg loads per step with depth-8 rotating prefetch; exp2 constants
// folded into weights at load). Publishes e(t) into ping-pong LDS ebuf; one
// barrier per 8 steps. Waves 1-4 decode group g while the producer computes
// g+1. k2's wall time = latency of ONE 1024-step chain (all rows parallel
// across blocks) -- r15/r17/r18 structural variants all regressed.
__global__ __launch_bounds__(320) void k2_fused(
    const float* __restrict__ e0, const float* __restrict__ W_hh,
    const float* __restrict__ b_hh, const float* __restrict__ xg,
    const float* __restrict__ h_seq, const float* __restrict__ W_dec,
    const float* __restrict__ b_dec, float* __restrict__ partials)
{
  __shared__ float ebuf[2][P_][H_];   // 1280 B ping-pong
  __shared__ float red[8];
  const int b = blockIdx.x;
  const int tid = threadIdx.x;
  const int lane = tid & 63;
  const int wave = tid >> 6;
  float acc = 0.f;   // producer wave leaves 0

  if (wave == 0) {
    // ---------------- producer: recurrence ----------------
    const bool own = lane < H_;
    const int j0 = own ? lane : 0;

    float2 wr2[10], wz2[10], wn2[10];
    #pragma unroll
    for (int k = 0; k < 10; ++k) {
      const float2 a = *(const float2*)&W_hh[j0 * H_ + 2 * k];
      const float2 c = *(const float2*)&W_hh[(j0 + 20) * H_ + 2 * k];
      const float2 d = *(const float2*)&W_hh[(j0 + 40) * H_ + 2 * k];
      wr2[k] = make_float2(a.x * NL2E_, a.y * NL2E_);
      wz2[k] = make_float2(c.x * NL2E_, c.y * NL2E_);
      wn2[k] = make_float2(d.x * L2E2_, d.y * L2E2_);
    }
    const float bhr = b_hh[j0] * NL2E_;
    const float bhz = b_hh[j0 + 20] * NL2E_;
    const float bhn = b_hh[j0 + 40] * L2E2_;

    float e_own = e0[b * H_ + j0];
    float2 es2[10];
    #pragma unroll
    for (int k = 0; k < 10; ++k) {
      es2[k].x = rdlane(e_own, 2 * k);
      es2[k].y = rdlane(e_own, 2 * k + 1);
    }

    const float* xgb = xg + (size_t)b * T_ * G_;
    float xr[P_], xz[P_], xn[P_];
    #pragma unroll
    for (int j = 0; j < P_; ++j) {
      xr[j] = xgb[(size_t)j * G_ + j0] * NL2E_;
      xz[j] = xgb[(size_t)j * G_ + j0 + 20] * NL2E_;
      xn[j] = xgb[(size_t)j * G_ + j0 + 40] * L2E2_;
    }

#define STEP(j, RELOAD)                                                    \
    {                                                                      \
      const int t = t0 + (j);                                              \
      const float xrv = xr[j], xzv = xz[j], xnv = xn[j];                   \
      if (RELOAD) {                                                        \
        const float* xp = xgb + (size_t)(t + P_) * G_;                     \
        xr[j] = xp[j0] * NL2E_;                                            \
        xz[j] = xp[j0 + 20] * NL2E_;                                       \
        xn[j] = xp[j0 + 40] * L2E2_;                                       \
      }                                                                    \
      float2 rA = make_float2(bhr, 0.f), rB = make_float2(0.f, 0.f);       \
      float2 zA = make_float2(bhz, 0.f), zB = make_float2(0.f, 0.f);       \
      float2 nA = make_float2(bhn, 0.f), nB = make_float2(0.f, 0.f);       \
      _Pragma("unroll")                                                    \
      for (int k = 0; k < 5; ++k) {                                        \
        rA = wr2[k] * es2[k] + rA;   rB = wr2[k + 5] * es2[k + 5] + rB;    \
        zA = wz2[k] * es2[k] + zA;   zB = wz2[k + 5] * es2[k + 5] + zB;    \
        nA = wn2[k] * es2[k] + nA;   nB = wn2[k + 5] * es2[k + 5] + nB;    \
      }                                                                    \
      const float hr2 = (rA.x + rB.x) + (rA.y + rB.y);                     \
      const float hz2 = (zA.x + zB.x) + (zA.y + zB.y);                     \
      const float hn2 = (nA.x + nB.x) + (nA.y + nB.y);                     \
      const float rg = RCP(1.f + EXP2(xrv + hr2));                         \
      const float zg = RCP(1.f + EXP2(xzv + hz2));                         \
      const float aa2 = fmaf(rg, hn2, xnv);                                \
      const float ng = fmaf(-2.f, RCP(EXP2(aa2) + 1.f), 1.f);              \
      const float enew = fmaf(zg, e_own - ng, ng);                         \
      if (own) ebuf[(t0 >> 3) & 1][j][lane] = enew;                        \
      e_own = enew;                                                        \
      _Pragma("unroll")                                                    \
      for (int k = 0; k < 10; ++k) {                                       \
        es2[k].x = rdlane(enew, 2 * k);                                    \
        es2[k].y = rdlane(enew, 2 * k + 1);                                \
      }                                                                    \
    }

    for (int t0 = 0; t0 < T_ - P_; t0 += P_) {
      STEP(0, true) STEP(1, true) STEP(2, true) STEP(3, true)
      STEP(4, true) STEP(5, true) STEP(6, true) STEP(7, true)
      __syncthreads();                 // publish group t0/8
    }
    {
      const int t0 = T_ - P_;
      STEP(0, false) STEP(1, false) STEP(2, false) STEP(3, false)
      STEP(4, false) STEP(5, false) STEP(6, false) STEP(7, false)
      __syncthreads();                 // publish last group
    }
#undef STEP
  } else {
    // ---------------- consumers: decoder + squared error ----------------
    const int ct = tid - 64;           // 0..255
    const bool act = ct < F_;
    const int f = act ? ct : 0;
    float wd[H_];
    #pragma unroll
    for (int k = 0; k < H_; ++k) wd[k] = W_dec[f * H_ + k];
    const float bd = b_dec[f];
    const float* hsb = h_seq + (size_t)b * T_ * HS_;

    float hcur[P_], hnxt[P_];
    #pragma unroll
    for (int j = 0; j < P_; ++j) hcur[j] = hsb[(size_t)j * HS_ + f];

    for (int g = 0; g < T_ / P_; ++g) {
      __syncthreads();                 // ebuf group g published
      if (g < T_ / P_ - 1) {
        #pragma unroll
        for (int j = 0; j < P_; ++j)
          hnxt[j] = hsb[(size_t)(P_ * (g + 1) + j) * HS_ + f];
      }
      const float* eb = &ebuf[g & 1][0][0];
      #pragma unroll
      for (int j = 0; j < P_; ++j) {
        const float2* ep = (const float2*)&eb[j * H_];
        float d = bd;
        #pragma unroll
        for (int k = 0; k < 10; ++k) {
          const float2 e2 = ep[k];
          d = fmaf(wd[2 * k], e2.x, fmaf(wd[2 * k + 1], e2.y, d));
        }
        const float fo = fmaxf(d, 0.f);
        const float df = fo - hcur[j];
        if (act) acc = fmaf(df, df, acc);
      }
      #pragma unroll
      for (int j = 0; j < P_; ++j) hcur[j] = hnxt[j];
    }
  }

  // deterministic block reduction (producer contributes 0)
  #pragma unroll
  for (int m = 32; m >= 1; m >>= 1) acc += __shfl_xor(acc, m);
  if (lane == 0) red[wave] = acc;
  __syncthreads();
  if (tid == 0)
    partials[b] = ((red[0] + red[1]) + (red[2] + red[3])) + red[4];
}

// ---------------- K3: final deterministic reduction over 128 partials ----------------
__global__ __launch_bounds__(64) void k3_reduce(
    const float* __restrict__ partials, float* __restrict__ out)
{
  const int lane = threadIdx.x;
  float a = partials[lane] + partials[lane + 64];
  #pragma unroll
  for (int m = 32; m >= 1; m >>= 1) a += __shfl_xor(a, m);
  if (lane == 0) out[0] = a * (float)(1.0 / ((double)T_ * B_ * F_));
}

extern "C" void kernel_launch(void* const* d_in, const int* in_sizes, int n_in,
                              void* d_out, int out_size, void* d_ws, size_t ws_size,
                              hipStream_t stream) {
  const float* feats = (const float*)d_in[0];
  const float* e0    = (const float*)d_in[1];
  const float* W_ih  = (const float*)d_in[2];
  const float* W_hh  = (const float*)d_in[3];
  const float* b_ih  = (const float*)d_in[4];
  const float* b_hh  = (const float*)d_in[5];
  const float* W_dec = (const float*)d_in[6];
  const float* b_dec = (const float*)d_in[7];
  float* out = (float*)d_out;

  float* ws = (float*)d_ws;
  float* h_seq    = ws;                                    // B*T*HS_ floats (b-major, padded)
  float* xgates   = ws + (size_t)B_ * T_ * HS_;            // B*T*G floats (b-major)
  float* partials = xgates + (size_t)B_ * T_ * G_;         // 128 floats
  float* Wt       = partials + 128;                        // FP_*G_ floats

  hipLaunchKernelGGL(k1a_pool, dim3(T_ * (B_ / 8)), dim3(256), 0, stream,
                     feats, h_seq, W_ih, Wt);
  hipLaunchKernelGGL(k1b_gemm, dim3(B_ * 16), dim3(256), 0, stream,
                     h_seq, Wt, b_ih, xgates);
  hipLaunchKernelGGL(k2_fused, dim3(B_), dim3(320), 0, stream,
                     e0, W_hh, b_hh, xgates, h_seq, W_dec, b_dec, partials);
  hipLaunchKernelGGL(k3_reduce, dim3(1), dim3(64), 0, stream,
                     partials, out);
}